// Round 5
// baseline (663.013 us; speedup 1.0000x reference)
//
#include <hip/hip_runtime.h>

#define NP 25088   // B * oH * oW = 8*56*56
#define DD 576     // 64 * 3 * 3
#define KC 256     // centroids

// ---------------- unfold: x[8,64,56,56] -> P^T[576][25088], d = c*9+i*3+j ----
__global__ __launch_bounds__(256) void unfold_kernel(const float* __restrict__ x,
                                                     float* __restrict__ PT) {
  const int d = blockIdx.y;                       // 0..575
  const int n = blockIdx.x * 256 + threadIdx.x;   // 0..25087
  const int c = d / 9, r = d % 9;
  const int di = r / 3 - 1, dj = r % 3 - 1;
  const int b = n / 3136, hw = n % 3136;
  const int h = hw / 56 + di, w = hw % 56 + dj;
  float v = 0.0f;
  if (h >= 0 && h < 56 && w >= 0 && w < 56)
    v = x[(((size_t)b * 64 + c) * 56 + h) * 56 + w];
  PT[(size_t)d * NP + n] = v;
}

// ---------------- centroid transpose: C[256][576] -> C^T[576][256] -----------
__global__ __launch_bounds__(256) void transpose_kernel(const float* __restrict__ C,
                                                        float* __restrict__ CT) {
  const int d = blockIdx.x;      // 576
  const int k = threadIdx.x;     // 256
  CT[d * KC + k] = C[k * DD + d];
}

// ---------------- nearest: per-block best over a 128-k slab ------------------
// block: 64 patches x 128 centroids. 784 blocks (392 m-groups x 2 k-slabs),
// XCD-chunk swizzled. LDS 48 KB -> 3 blocks/CU, 12 waves/CU.
// 256 threads, thread tile 4m x 8k: per d, 3 ds_read_b128 feed 64 VALU instr
// (R4's 4m x 4k was 2 reads / 32 instr -> LDS-pipe co-saturated with VALU).
// B per-thread k-set {tk*4+j, 64+tk*4+j}: both reads 2-way bank-aliased (free).
// ALL per-thread state is named float4 scalars (R4: arrays => scratch).
// part/tot split accumulation (64-d segments) for argmin tie accuracy.
#define ACC4(p, a, s) \
  do { p.x += fabsf(a.x - (s)); p.y += fabsf(a.y - (s)); \
       p.z += fabsf(a.z - (s)); p.w += fabsf(a.w - (s)); } while (0)
#define ADD4(t, p) \
  do { t.x += p.x; t.y += p.y; t.z += p.z; t.w += p.w; } while (0)
#define COMP(v, i) ((i) == 0 ? (v).x : (i) == 1 ? (v).y : (i) == 2 ? (v).z : (v).w)

__global__ __launch_bounds__(256, 3) void nearest_kernel(const float* __restrict__ AT,
                                                         const float* __restrict__ CT,
                                                         float* __restrict__ distc,
                                                         int* __restrict__ idxc) {
  __shared__ float As[2][32][64];    // [buf][d][m]   16 KB
  __shared__ float Bs[2][32][128];   // [buf][d][k]   32 KB

  const int tid = threadIdx.x;
  const int tm = tid >> 4;           // 0..15 -> m = m0 + tm*4 + i
  const int tk = tid & 15;           // 0..15 -> k = k0 + {tk*4+j, 64+tk*4+j}
  // XCD-chunk swizzle: XCD x gets m-groups [49x, 49x+49), both k-slabs adjacent.
  const int L = blockIdx.x;          // 0..783 (= 8 * 98)
  const int xcd = L & 7, r = L >> 3;     // r 0..97
  const int mb = xcd * 49 + (r >> 1);    // 0..391
  const int kc = r & 1;                  // 0..1
  const int m0 = mb * 64, k0 = kc * 128;

  // staging + accumulators: named float4 only (no local arrays anywhere)
  float4 ra0, ra1, rb0, rb1, rb2, rb3;
  float4 p0, p1, p2, p3, p4, p5, p6, p7;
  float4 t0, t1, t2, t3, t4, t5, t6, t7;

  const int arow = tid >> 4, acol = (tid & 15) * 4;   // A rows arow, arow+16
  const int brow = tid >> 5, bcol = (tid & 31) * 4;   // B rows brow+{0,8,16,24}
  const float* ap = AT + (size_t)arow * NP + m0 + acol;
  const float* bp = CT + (size_t)brow * KC + k0 + bcol;

#define LOADT() do {                                       \
    ra0 = *(const float4*)(ap);                            \
    ra1 = *(const float4*)(ap + (size_t)16 * NP);          \
    rb0 = *(const float4*)(bp);                            \
    rb1 = *(const float4*)(bp + 8 * KC);                   \
    rb2 = *(const float4*)(bp + 16 * KC);                  \
    rb3 = *(const float4*)(bp + 24 * KC);                  \
    ap += (size_t)32 * NP; bp += 32 * KC;                  \
  } while (0)

#define WRITET(bf) do {                                    \
    *(float4*)&As[bf][arow][acol] = ra0;                   \
    *(float4*)&As[bf][16 + arow][acol] = ra1;              \
    *(float4*)&Bs[bf][brow][bcol] = rb0;                   \
    *(float4*)&Bs[bf][8 + brow][bcol] = rb1;               \
    *(float4*)&Bs[bf][16 + brow][bcol] = rb2;              \
    *(float4*)&Bs[bf][24 + brow][bcol] = rb3;              \
  } while (0)

  LOADT();
  WRITET(0);
  t0 = t1 = t2 = t3 = t4 = t5 = t6 = t7 = make_float4(0.f, 0.f, 0.f, 0.f);

  for (int ch = 0; ch < 18; ++ch) {            // 18 * 32 = 576 d's
    if ((ch & 1) == 0)
      p0 = p1 = p2 = p3 = p4 = p5 = p6 = p7 = make_float4(0.f, 0.f, 0.f, 0.f);
    __syncthreads();                           // staged buf (ch&1) visible
    if (ch < 17) LOADT();                      // issue next-chunk global loads
    const float (*__restrict__ Asb)[64]  = As[ch & 1];
    const float (*__restrict__ Bsb)[128] = Bs[ch & 1];
#pragma unroll 4
    for (int d = 0; d < 32; ++d) {
      const float4 a = *(const float4*)&Asb[d][tm * 4];
      const float4 b = *(const float4*)&Bsb[d][tk * 4];
      const float4 c = *(const float4*)&Bsb[d][64 + tk * 4];
      ACC4(p0, a, b.x);
      ACC4(p1, a, b.y);
      ACC4(p2, a, b.z);
      ACC4(p3, a, b.w);
      ACC4(p4, a, c.x);
      ACC4(p5, a, c.y);
      ACC4(p6, a, c.z);
      ACC4(p7, a, c.w);
    }
    if (ch < 17) WRITET((ch + 1) & 1);         // ds_write after compute (T14)
    if (ch & 1) {                              // segment flush (64 d's)
      ADD4(t0, p0); ADD4(t1, p1); ADD4(t2, p2); ADD4(t3, p3);
      ADD4(t4, p4); ADD4(t5, p5); ADD4(t6, p6); ADD4(t7, p7);
    }
  }

  // per-thread argmin over its 8 k's (ascending k, strict < => first-min),
  // then butterfly reduce across the 16 tk lanes sharing this m-row.
#pragma unroll
  for (int i = 0; i < 4; ++i) {
    float bd = COMP(t0, i);
    int bk = k0 + tk * 4;
    float dj;
    dj = COMP(t1, i); if (dj < bd) { bd = dj; bk = k0 + tk * 4 + 1; }
    dj = COMP(t2, i); if (dj < bd) { bd = dj; bk = k0 + tk * 4 + 2; }
    dj = COMP(t3, i); if (dj < bd) { bd = dj; bk = k0 + tk * 4 + 3; }
    dj = COMP(t4, i); if (dj < bd) { bd = dj; bk = k0 + 64 + tk * 4; }
    dj = COMP(t5, i); if (dj < bd) { bd = dj; bk = k0 + 64 + tk * 4 + 1; }
    dj = COMP(t6, i); if (dj < bd) { bd = dj; bk = k0 + 64 + tk * 4 + 2; }
    dj = COMP(t7, i); if (dj < bd) { bd = dj; bk = k0 + 64 + tk * 4 + 3; }
#pragma unroll
    for (int off = 1; off < 16; off <<= 1) {
      const float od = __shfl_xor(bd, off, 64);
      const int ok = __shfl_xor(bk, off, 64);
      if (od < bd || (od == bd && ok < bk)) { bd = od; bk = ok; }
    }
    if (tk == 0) {
      const int m = m0 + tm * 4 + i;
      distc[(size_t)kc * NP + m] = bd;
      idxc[(size_t)kc * NP + m] = bk;
    }
  }
#undef LOADT
#undef WRITET
}

// ---------------- combine the two k-slab candidates (tie -> lower k) ---------
__global__ __launch_bounds__(256) void combine_kernel(const float* __restrict__ distc,
                                                      const int* __restrict__ idxc,
                                                      int* __restrict__ idx_out) {
  const int n = blockIdx.x * 256 + threadIdx.x;
  if (n >= NP) return;
  const float d0 = distc[n], d1 = distc[NP + n];
  idx_out[n] = (d1 < d0) ? idxc[NP + n] : idxc[n];   // tie keeps slab 0 (lower k)
}

// ---------------- residual in place: P^T[d][n] -= C1^T[d][idx1[n]] -----------
__global__ __launch_bounds__(256) void resid_kernel(float* __restrict__ PT,
                                                    const float* __restrict__ C1T,
                                                    const int* __restrict__ idx1) {
  const int d = blockIdx.y;
  const int n = blockIdx.x * 256 + threadIdx.x;
  const int k = idx1[n];
  PT[(size_t)d * NP + n] -= C1T[d * KC + k];
}

// ---------------- BN stats: per-channel sum & sumsq of LUT outputs -----------
__global__ __launch_bounds__(256) void stats_kernel(const int* __restrict__ idx1,
                                                    const int* __restrict__ idx2,
                                                    const float* __restrict__ dotc,
                                                    const float* __restrict__ dotrc,
                                                    float* __restrict__ gsum,
                                                    float* __restrict__ gsq) {
  __shared__ float ssum[4][128], ssq[4][128];
  const int tid = threadIdx.x, lane = tid & 63, wv = tid >> 6;
  const int wid = blockIdx.x * 4 + wv;           // 0..511
  float s0 = 0.f, s1 = 0.f, q0 = 0.f, q1 = 0.f;
  for (int n = wid; n < NP; n += 512) {          // 25088 = 512*49
    const int k1 = idx1[n], k2 = idx2[n];
    const float2 u = ((const float2*)(dotc + (size_t)k1 * 128))[lane];
    const float2 v = ((const float2*)(dotrc + (size_t)k2 * 128))[lane];
    const float x0 = u.x + v.x, x1 = u.y + v.y;
    s0 += x0; s1 += x1; q0 += x0 * x0; q1 += x1 * x1;
  }
  ssum[wv][lane * 2] = s0; ssum[wv][lane * 2 + 1] = s1;
  ssq[wv][lane * 2] = q0;  ssq[wv][lane * 2 + 1] = q1;
  __syncthreads();
  if (tid < 128) {
    const float s = ssum[0][tid] + ssum[1][tid] + ssum[2][tid] + ssum[3][tid];
    const float q = ssq[0][tid] + ssq[1][tid] + ssq[2][tid] + ssq[3][tid];
    atomicAdd(&gsum[tid], s);
    atomicAdd(&gsq[tid], q);
  }
}

__global__ void finalize_kernel(const float* __restrict__ gsum,
                                const float* __restrict__ gsq,
                                const float* __restrict__ gamma,
                                const float* __restrict__ beta,
                                float* __restrict__ scalev,
                                float* __restrict__ shiftv) {
  const int c = threadIdx.x;                     // 128
  const float mean = gsum[c] * (1.0f / NP);
  const float var = gsq[c] * (1.0f / NP) - mean * mean;
  const float inv = rsqrtf(var + 1e-5f);
  const float sc = gamma[c] * inv;
  scalev[c] = sc;
  shiftv[c] = beta[c] - mean * sc;
}

// ---------------- output: LUT gather + affine BN + [B,C,H,W] store -----------
__global__ __launch_bounds__(256) void output_kernel(const int* __restrict__ idx1,
                                                     const int* __restrict__ idx2,
                                                     const float* __restrict__ dotc,
                                                     const float* __restrict__ dotrc,
                                                     const float* __restrict__ scalev,
                                                     const float* __restrict__ shiftv,
                                                     float* __restrict__ out) {
  __shared__ float vals[64][128];                // [n-local][c]  32 KB
  const int tid = threadIdx.x, lane = tid & 63, wv = tid >> 6;
  const int blk = blockIdx.x;                    // 392 = 8 * 49
  const int b = blk / 49, hw0 = (blk % 49) * 64;
  const int n0 = b * 3136 + hw0;
  const float sc0 = scalev[lane * 2], sc1 = scalev[lane * 2 + 1];
  const float sh0 = shiftv[lane * 2], sh1 = shiftv[lane * 2 + 1];
  for (int t = 0; t < 16; ++t) {
    const int nn = wv * 16 + t;
    const int n = n0 + nn;
    const int k1 = idx1[n], k2 = idx2[n];
    const float2 u = ((const float2*)(dotc + (size_t)k1 * 128))[lane];
    const float2 v = ((const float2*)(dotrc + (size_t)k2 * 128))[lane];
    *(float2*)&vals[nn][lane * 2] =
        make_float2(sc0 * (u.x + v.x) + sh0, sc1 * (u.y + v.y) + sh1);
  }
  __syncthreads();
  const int c = tid >> 1, half = tid & 1;
  float* op = out + ((size_t)b * 128 + c) * 3136 + hw0 + half * 32;
#pragma unroll
  for (int i = 0; i < 32; i += 4) {
    float4 w4;
    w4.x = vals[half * 32 + i + 0][c];
    w4.y = vals[half * 32 + i + 1][c];
    w4.z = vals[half * 32 + i + 2][c];
    w4.w = vals[half * 32 + i + 3][c];
    *(float4*)(op + i) = w4;
  }
}

extern "C" void kernel_launch(void* const* d_in, const int* in_sizes, int n_in,
                              void* d_out, int out_size, void* d_ws, size_t ws_size,
                              hipStream_t stream) {
  const float* x     = (const float*)d_in[0];
  const float* cent  = (const float*)d_in[1];
  const float* rcent = (const float*)d_in[2];
  const float* dotc  = (const float*)d_in[3];
  const float* dotrc = (const float*)d_in[4];
  const float* gamma = (const float*)d_in[5];
  const float* beta  = (const float*)d_in[6];
  float* out = (float*)d_out;

  // workspace layout (~60 MB)
  float* PT  = (float*)d_ws;                 // [576][25088]
  float* C1T = PT + (size_t)DD * NP;         // [576][256]
  float* C2T = C1T + (size_t)DD * KC;        // [576][256]
  int* idx1  = (int*)(C2T + (size_t)DD * KC);
  int* idx2  = idx1 + NP;
  float* distc = (float*)(idx2 + NP);        // [2][25088]
  int* idxc    = (int*)(distc + 2 * NP);     // [2][25088]
  float* gsum   = (float*)(idxc + 2 * NP);   // [128]
  float* gsq    = gsum + 128;                // [128]
  float* scalev = gsq + 128;                 // [128]
  float* shiftv = scalev + 128;              // [128]

  unfold_kernel<<<dim3(98, 576), 256, 0, stream>>>(x, PT);
  transpose_kernel<<<576, 256, 0, stream>>>(cent, C1T);
  transpose_kernel<<<576, 256, 0, stream>>>(rcent, C2T);
  nearest_kernel<<<784, 256, 0, stream>>>(PT, C1T, distc, idxc);
  combine_kernel<<<98, 256, 0, stream>>>(distc, idxc, idx1);
  resid_kernel<<<dim3(98, 576), 256, 0, stream>>>(PT, C1T, idx1);
  nearest_kernel<<<784, 256, 0, stream>>>(PT, C2T, distc, idxc);
  combine_kernel<<<98, 256, 0, stream>>>(distc, idxc, idx2);
  hipMemsetAsync(gsum, 0, 256 * sizeof(float), stream);
  stats_kernel<<<128, 256, 0, stream>>>(idx1, idx2, dotc, dotrc, gsum, gsq);
  finalize_kernel<<<1, 128, 0, stream>>>(gsum, gsq, gamma, beta, scalev, shiftv);
  output_kernel<<<392, 256, 0, stream>>>(idx1, idx2, dotc, dotrc, scalev, shiftv, out);
}